// Round 7
// baseline (377.807 us; speedup 1.0000x reference)
//
#include <hip/hip_runtime.h>
#include <math.h>

#define NN 100000
#define NE 1600000
#define DD 64
#define NBUK 782          // ceil(NN/128) scan chunks
#define CNT_BLKS ((NE + 255) / 256)   // 6250

typedef __attribute__((ext_vector_type(8))) short short8;
typedef __attribute__((ext_vector_type(4))) float f32x4;
typedef __attribute__((ext_vector_type(4))) _Float16 h4;
typedef __attribute__((ext_vector_type(2))) _Float16 f16x2;

__device__ __forceinline__ float gelu_exact(float v) {
    return 0.5f * v * (1.0f + erff(v * 0.7071067811865475f));
}

__device__ __forceinline__ unsigned short f2bf(float f) {   // RNE
    unsigned u = __float_as_uint(f);
    return (unsigned short)((u + 0x7FFFu + ((u >> 16) & 1u)) >> 16);
}
__device__ __forceinline__ float bf2f(unsigned short h) {
    return __uint_as_float((unsigned)h << 16);
}
__device__ __forceinline__ void split8v(float4 x0, float4 x1, short8& hi, short8& lo) {
    float v[8] = {x0.x, x0.y, x0.z, x0.w, x1.x, x1.y, x1.z, x1.w};
    #pragma unroll
    for (int i = 0; i < 8; ++i) {
        unsigned short h = f2bf(v[i]);
        hi[i] = (short)h;
        lo[i] = (short)f2bf(v[i] - bf2f(h));
    }
}
// read 8 consecutive floats (k0 = u0*4) from a unit-XOR-swizzled 16x64 tile
__device__ __forceinline__ void lds_frag(const float* g, int row, int u0, int s,
                                         short8& hi, short8& lo) {
    float4 p0 = *(const float4*)&g[row * 64 + ((u0 ^ s) << 2)];
    float4 p1 = *(const float4*)&g[row * 64 + (((u0 + 1) ^ s) << 2)];
    split8v(p0, p1, hi, lo);
}

__device__ __forceinline__ f16x2 as_f16x2(unsigned int u) {
    union { unsigned int x; f16x2 h; } c; c.x = u; return c.h;
}
__device__ __forceinline__ unsigned short h_as_us(_Float16 h) {
    union { _Float16 h; unsigned short u; } c; c.h = h; return c.u;
}
__device__ __forceinline__ float us_as_f(unsigned short u) {
    union { unsigned short u; _Float16 h; } c; c.u = u; return (float)c.h;
}

// K01: fused weight-prep (blocks <96) + attention proj/fp16-x (96..486)
//      + edge degree count (487..) — cnt pre-zeroed by memset.
__global__ __launch_bounds__(256) void k01(
    const float* __restrict__ Wp, const float* __restrict__ Wn,
    const float* __restrict__ w1, const float* __restrict__ w2,
    const float* __restrict__ cf,
    unsigned short* __restrict__ wh, unsigned short* __restrict__ wl,
    const float* __restrict__ x, const float* __restrict__ attw,
    float* __restrict__ es1, _Float16* __restrict__ xh,
    const int* __restrict__ ei, int* __restrict__ cnt)
{
    int bid = blockIdx.x;
    if (bid < 96) {
        int t = bid * 256 + threadIdx.x;   // 24576 total
        float alpha = 1.0f / (1.0f + __expf(-cf[0]));
        float beta  = 1.0f - alpha;
        float v;
        if (t < 8192) {
            int d = t >> 7, k = t & 127;
            v = (k < 64) ? alpha * Wp[d * 64 + k] : beta * Wn[d * 64 + (k - 64)];
        } else if (t < 16384) {
            v = w1[t - 8192];
        } else {
            v = w2[t - 16384];
        }
        unsigned short h = f2bf(v);
        wh[t] = h;
        wl[t] = f2bf(v - bf2f(h));
    } else if (bid < 487) {
        int n = (bid - 96) * 256 + threadIdx.x;
        if (n >= NN) return;
        const float4* x4 = (const float4*)(x + (size_t)n * DD);
        float a = 0.f;
        #pragma unroll
        for (int i = 0; i < DD/4; ++i) {
            float4 v = x4[i];
            a += v.x*attw[4*i+0] + v.y*attw[4*i+1] + v.z*attw[4*i+2] + v.w*attw[4*i+3];
            h4 hv = {(_Float16)v.x, (_Float16)v.y, (_Float16)v.z, (_Float16)v.w};
            *(h4*)(xh + (size_t)n * DD + 4*i) = hv;
        }
        es1[n] = __expf(a);
    } else {
        int e = (bid - 487) * 256 + threadIdx.x;
        if (e < NE) atomicAdd(&cnt[ei[NE + e]], 1);
    }
}

// KA: per-128-chunk reduce of cnt -> bsum
__global__ __launch_bounds__(128) void kA(
    const int* __restrict__ cnt, int* __restrict__ bsum)
{
    __shared__ int part[2];
    int b = blockIdx.x, t = threadIdx.x;
    int i = b * 128 + t;
    int v = (i < NN) ? cnt[i] : 0;
    #pragma unroll
    for (int o = 32; o > 0; o >>= 1) v += __shfl_xor(v, o);
    if ((t & 63) == 0) part[t >> 6] = v;
    __syncthreads();
    if (t == 0) bsum[b] = part[0] + part[1];
}

// KB: single-block exclusive scan of 782 chunk sums -> bbase
__global__ __launch_bounds__(1024) void kB(
    const int* __restrict__ bsum, int* __restrict__ bbase)
{
    __shared__ int sa[1024], sb[1024];
    int t = threadIdx.x;
    int v = (t < NBUK) ? bsum[t] : 0;
    sa[t] = v;
    __syncthreads();
    int* s = sa; int* d = sb;
    #pragma unroll
    for (int o = 1; o < 1024; o <<= 1) {
        d[t] = s[t] + ((t >= o) ? s[t - o] : 0);
        __syncthreads();
        int* tmp = s; s = d; d = tmp;
    }
    if (t < NBUK) bbase[t] = s[t] - v;
    if (t == 0) bbase[NBUK] = NE;
}

// KC: expand — off[i] = bbase[b] + local exclusive scan; cur = off copy
__global__ __launch_bounds__(128) void kC(
    const int* __restrict__ cnt, const int* __restrict__ bbase,
    int* __restrict__ off, int* __restrict__ cur)
{
    __shared__ int w0tot;
    int b = blockIdx.x, t = threadIdx.x;
    int i = b * 128 + t;
    int v = (i < NN) ? cnt[i] : 0;
    int xsc = v;
    #pragma unroll
    for (int o = 1; o < 64; o <<= 1) {
        int up = __shfl_up(xsc, o);
        if ((t & 63) >= o) xsc += up;
    }
    if (t == 63) w0tot = xsc;
    __syncthreads();
    if (t >= 64) xsc += w0tot;
    int excl = bbase[b] + xsc - v;
    if (i < NN) { off[i] = excl; cur[i] = excl; }
    if (b == NBUK - 1 && t == 127) off[NN] = NE;
}

// KS: direct scatter. sorted[p] = {src, fp16x2(es, es*rf)}; p via per-node ticket.
__global__ __launch_bounds__(256) void kS(
    const int* __restrict__ ei, const float* __restrict__ rf,
    const float* __restrict__ es1, int* __restrict__ cur,
    uint2* __restrict__ sorted)
{
    int e = blockIdx.x * 256 + threadIdx.x;
    if (e >= NE) return;
    int src = ei[e];
    int dst = ei[NE + e];
    float es = es1[src];
    float ef = es * rf[e];
    unsigned packed = (unsigned)h_as_us((_Float16)es)
                    | ((unsigned)h_as_us((_Float16)ef) << 16);
    int p = atomicAdd(&cur[dst], 1);
    sorted[p] = make_uint2((unsigned)src, packed);
}

// K4A v3: wave-per-node. Edge stream is wave-UNIFORM (readfirstlane bounds ->
// s_load via SMEM pipe; no ds_bpermute broadcasts). Math via v_dot2_f32_f16:
// per edge-pair {2 fp16 gathers packed to 1 dword, 3 fdot2} ~= 2 VALU/edge.
__global__ __launch_bounds__(256) void k4a_agg(
    const uint2* __restrict__ sorted, const int* __restrict__ off,
    const _Float16* __restrict__ xh, float* __restrict__ uv)
{
    int lane = threadIdx.x & 63;
    int n = blockIdx.x * 4 + (threadIdx.x >> 6);
    int r0 = __builtin_amdgcn_readfirstlane(off[n]);
    int r1 = __builtin_amdgcn_readfirstlane(off[n + 1]);
    const unsigned short* xs = (const unsigned short*)xh;

    float den = 0.f, u = 0.f, v = 0.f;
    const unsigned ONES = 0x3C003C00u;   // fp16x2 {1,1}
    int j = r0;
    for (; j + 8 <= r1; j += 8) {
        uint2 p[8];
        #pragma unroll
        for (int t = 0; t < 8; ++t) p[t] = sorted[j + t];
        unsigned xv[4];
        #pragma unroll
        for (int q = 0; q < 4; ++q) {
            unsigned a0 = xs[(size_t)p[2*q].x   * DD + lane];
            unsigned a1 = xs[(size_t)p[2*q+1].x * DD + lane];
            xv[q] = a0 | (a1 << 16);
        }
        #pragma unroll
        for (int q = 0; q < 4; ++q) {
            unsigned y0 = p[2*q].y, y1 = p[2*q+1].y;
            unsigned e2 = (y0 & 0xFFFFu) | (y1 << 16);
            unsigned f2 = (y0 >> 16) | (y1 & 0xFFFF0000u);
            v   = __builtin_amdgcn_fdot2(as_f16x2(xv[q]), as_f16x2(e2), v, false);
            u   = __builtin_amdgcn_fdot2(as_f16x2(xv[q]), as_f16x2(f2), u, false);
            den = __builtin_amdgcn_fdot2(as_f16x2(e2), as_f16x2(ONES), den, false);
        }
    }
    for (; j + 2 <= r1; j += 2) {
        uint2 p0 = sorted[j], p1 = sorted[j + 1];
        unsigned a0 = xs[(size_t)p0.x * DD + lane];
        unsigned a1 = xs[(size_t)p1.x * DD + lane];
        unsigned xv = a0 | (a1 << 16);
        unsigned e2 = (p0.y & 0xFFFFu) | (p1.y << 16);
        unsigned f2 = (p0.y >> 16) | (p1.y & 0xFFFF0000u);
        v   = __builtin_amdgcn_fdot2(as_f16x2(xv), as_f16x2(e2), v, false);
        u   = __builtin_amdgcn_fdot2(as_f16x2(xv), as_f16x2(f2), u, false);
        den = __builtin_amdgcn_fdot2(as_f16x2(e2), as_f16x2(ONES), den, false);
    }
    if (j < r1) {
        uint2 p0 = sorted[j];
        float xvf = us_as_f((unsigned short)xs[(size_t)p0.x * DD + lane]);
        float e = us_as_f((unsigned short)(p0.y & 0xFFFFu));
        float f = us_as_f((unsigned short)(p0.y >> 16));
        den += e; v += e * xvf; u += f * xvf;
    }
    float inv = (r1 > r0) ? 1.f / den : 0.f;
    uv[(size_t)n * 128 + lane]      = u * inv;
    uv[(size_t)n * 128 + 64 + lane] = v * inv;
}

// K4B5 (unchanged from r5): 512 threads / 8 waves / 128 nodes per block.
__global__ __launch_bounds__(512, 4) void k4b5(
    const float* __restrict__ uv,
    const unsigned short* __restrict__ wh, const unsigned short* __restrict__ wl,
    const float* __restrict__ x,
    const float* __restrict__ g1, const float* __restrict__ be1,
    const float* __restrict__ bb1, const float* __restrict__ bb2,
    const float* __restrict__ g2, const float* __restrict__ be2,
    float* __restrict__ out)
{
    __shared__ unsigned short WH[8192], WL[8192];   // Bmix 64x128 / w1 128x64
    __shared__ unsigned short W2H[4096], W2L[4096]; // w2 k-half 64x64
    __shared__ float Gt[8][1024];                   // per-wave 16x64 (h / Ga / Gb)

    int tid  = threadIdx.x;
    int lane = tid & 63;
    int wv   = tid >> 6;
    int quad = lane >> 4, l16 = lane & 15;
    int s7   = l16 & 7;
    int nb = blockIdx.x * 128 + wv * 16;
    float* gt = Gt[wv];

    const float4* arow4 = (const float4*)(uv + (size_t)min(nb + l16, NN - 1) * 128);
    float4 av[8];
    #pragma unroll
    for (int ks = 0; ks < 4; ++ks) {
        av[2*ks]   = arow4[ks*8 + quad*2];
        av[2*ks+1] = arow4[ks*8 + quad*2 + 1];
    }
    float xr[4][4];
    #pragma unroll
    for (int r = 0; r < 4; ++r) {
        size_t nld = (size_t)min(nb + quad*4 + r, NN - 1) * 64;
        #pragma unroll
        for (int nt = 0; nt < 4; ++nt) xr[r][nt] = x[nld + nt*16 + l16];
    }

    #pragma unroll
    for (int k = 0; k < 2; ++k) {
        int i = tid + k*512;                 // 0..1023
        int row = i >> 4, u = i & 15;
        int up = u ^ (row & 7);
        *(short8*)&WH[row*128 + up*8] = *(const short8*)&wh[i*8];
        *(short8*)&WL[row*128 + up*8] = *(const short8*)&wl[i*8];
    }
    __syncthreads();

    f32x4 acc0[4] = {};
    #pragma unroll
    for (int ks = 0; ks < 4; ++ks) {
        short8 ah, al;
        split8v(av[2*ks], av[2*ks+1], ah, al);
        int u0 = 4*ks + quad;
        #pragma unroll
        for (int nt = 0; nt < 4; ++nt) {
            int wo = (nt*16 + l16)*128 + (u0 ^ s7)*8;
            short8 bh = *(const short8*)&WH[wo];
            short8 bl = *(const short8*)&WL[wo];
            acc0[nt] = __builtin_amdgcn_mfma_f32_16x16x32_bf16(ah, bh, acc0[nt], 0, 0, 0);
            acc0[nt] = __builtin_amdgcn_mfma_f32_16x16x32_bf16(al, bh, acc0[nt], 0, 0, 0);
            acc0[nt] = __builtin_amdgcn_mfma_f32_16x16x32_bf16(ah, bl, acc0[nt], 0, 0, 0);
        }
    }

    float hn[4][4];
    #pragma unroll
    for (int r = 0; r < 4; ++r) {
        float hv[4];
        #pragma unroll
        for (int nt = 0; nt < 4; ++nt)
            hv[nt] = gelu_exact(acc0[nt][r]) + xr[r][nt];
        float s = hv[0] + hv[1] + hv[2] + hv[3];
        #pragma unroll
        for (int o = 1; o < 16; o <<= 1) s += __shfl_xor(s, o);
        float mu = s * (1.0f/64.0f);
        float q = 0.f;
        #pragma unroll
        for (int nt = 0; nt < 4; ++nt) { float t = hv[nt] - mu; q += t*t; }
        #pragma unroll
        for (int o = 1; o < 16; o <<= 1) q += __shfl_xor(q, o);
        float rs = rsqrtf(q * (1.0f/64.0f) + 1e-5f);
        int row = quad*4 + r;
        #pragma unroll
        for (int nt = 0; nt < 4; ++nt) {
            int c = nt*16 + l16;
            float h = (hv[nt] - mu) * rs * g1[c] + be1[c];
            hn[r][nt] = h;
            int u = c >> 2;
            gt[row*64 + ((u ^ (row & 7)) << 2) + (c & 3)] = h;
        }
    }
    __syncthreads();    // all waves done reading Bmix

    #pragma unroll
    for (int k = 0; k < 2; ++k) {
        int i = tid + k*512;                 // 0..1023
        int row = i >> 3, u = i & 7;
        int up = u ^ (row & 7);
        *(short8*)&WH[row*64 + up*8] = *(const short8*)&wh[8192 + i*8];
        *(short8*)&WL[row*64 + up*8] = *(const short8*)&wl[8192 + i*8];
    }
    {
        int row = tid >> 3, u = tid & 7;     // 512 units
        int up = u ^ (row & 7);
        *(short8*)&W2H[row*64 + up*8] = *(const short8*)&wh[16384 + row*128 + u*8];
        *(short8*)&W2L[row*64 + up*8] = *(const short8*)&wl[16384 + row*128 + u*8];
    }
    __syncthreads();

    short8 ah1[2], al1[2];
    #pragma unroll
    for (int ks = 0; ks < 2; ++ks)
        lds_frag(gt, l16, 8*ks + 2*quad, s7, ah1[ks], al1[ks]);

    f32x4 acc2[4] = {};
    #pragma unroll
    for (int half = 0; half < 2; ++half) {
        f32x4 a1[4] = {};
        #pragma unroll
        for (int ks = 0; ks < 2; ++ks) {
            int u0 = 4*ks + quad;
            #pragma unroll
            for (int t = 0; t < 4; ++t) {
                int row = half*64 + t*16 + l16;
                int wo = row*64 + ((u0 ^ s7))*8;
                short8 bh = *(const short8*)&WH[wo];
                short8 bl = *(const short8*)&WL[wo];
                a1[t] = __builtin_amdgcn_mfma_f32_16x16x32_bf16(ah1[ks], bh, a1[t], 0, 0, 0);
                a1[t] = __builtin_amdgcn_mfma_f32_16x16x32_bf16(al1[ks], bh, a1[t], 0, 0, 0);
                a1[t] = __builtin_amdgcn_mfma_f32_16x16x32_bf16(ah1[ks], bl, a1[t], 0, 0, 0);
            }
        }
        #pragma unroll
        for (int t = 0; t < 4; ++t) {
            float b1v = bb1[half*64 + t*16 + l16];
            #pragma unroll
            for (int r = 0; r < 4; ++r) {
                int row = quad*4 + r;
                int c = t*16 + l16;
                int u = c >> 2;
                gt[row*64 + ((u ^ (row & 7)) << 2) + (c & 3)] = gelu_exact(a1[t][r] + b1v);
            }
        }
        #pragma unroll
        for (int ks2 = 0; ks2 < 2; ++ks2) {
            short8 ah2, al2;
            lds_frag(gt, l16, 8*ks2 + 2*quad, s7, ah2, al2);
            int u0 = 4*ks2 + quad;
            #pragma unroll
            for (int nt2 = 0; nt2 < 4; ++nt2) {
                int wo = (nt2*16 + l16)*64 + (u0 ^ s7)*8;
                short8 bh = *(const short8*)&W2H[wo];
                short8 bl = *(const short8*)&W2L[wo];
                acc2[nt2] = __builtin_amdgcn_mfma_f32_16x16x32_bf16(ah2, bh, acc2[nt2], 0, 0, 0);
                acc2[nt2] = __builtin_amdgcn_mfma_f32_16x16x32_bf16(al2, bh, acc2[nt2], 0, 0, 0);
                acc2[nt2] = __builtin_amdgcn_mfma_f32_16x16x32_bf16(ah2, bl, acc2[nt2], 0, 0, 0);
            }
        }
        if (half == 0) {
            __syncthreads();   // all waves done with w2 half A
            int row = tid >> 3, u = tid & 7;
            int up = u ^ (row & 7);
            *(short8*)&W2H[row*64 + up*8] = *(const short8*)&wh[16384 + row*128 + 64 + u*8];
            *(short8*)&W2L[row*64 + up*8] = *(const short8*)&wl[16384 + row*128 + 64 + u*8];
            __syncthreads();
        }
    }

    #pragma unroll
    for (int r = 0; r < 4; ++r) {
        int n = nb + quad * 4 + r;
        float mv[4];
        #pragma unroll
        for (int nt = 0; nt < 4; ++nt)
            mv[nt] = acc2[nt][r] + hn[r][nt] + bb2[nt*16 + l16];
        float s = mv[0] + mv[1] + mv[2] + mv[3];
        #pragma unroll
        for (int o = 1; o < 16; o <<= 1) s += __shfl_xor(s, o);
        float mu = s * (1.0f/64.0f);
        float q = 0.f;
        #pragma unroll
        for (int nt = 0; nt < 4; ++nt) { float t = mv[nt] - mu; q += t*t; }
        #pragma unroll
        for (int o = 1; o < 16; o <<= 1) q += __shfl_xor(q, o);
        float rs = rsqrtf(q * (1.0f/64.0f) + 1e-5f);
        if (n < NN) {
            #pragma unroll
            for (int nt = 0; nt < 4; ++nt) {
                int c = nt*16 + l16;
                out[(size_t)n * 64 + c] = (mv[nt] - mu) * rs * g2[c] + be2[c];
            }
        }
    }
}

extern "C" void kernel_launch(void* const* d_in, const int* in_sizes, int n_in,
                              void* d_out, int out_size, void* d_ws, size_t ws_size,
                              hipStream_t stream) {
    const float* x    = (const float*)d_in[0];
    const int*   ei   = (const int*)d_in[1];
    const float* rf   = (const float*)d_in[2];
    const float* Wp   = (const float*)d_in[3];
    const float* Wn   = (const float*)d_in[4];
    const float* attw = (const float*)d_in[5];
    const float* cf   = (const float*)d_in[6];
    const float* w1   = (const float*)d_in[7];
    const float* b1   = (const float*)d_in[8];
    const float* w2   = (const float*)d_in[9];
    const float* b2   = (const float*)d_in[10];
    const float* g1   = (const float*)d_in[11];
    const float* be1  = (const float*)d_in[12];
    const float* g2   = (const float*)d_in[13];
    const float* be2  = (const float*)d_in[14];
    float* out = (float*)d_out;

    float* ws = (float*)d_ws;
    float*  es1    = ws;                                   // NN
    float*  uv     = es1 + NN;                             // NN*128
    unsigned short* wh = (unsigned short*)(uv + (size_t)NN * 128);   // 24576 u16
    unsigned short* wl = wh + 24576;                                 // 24576 u16
    uint2*  sorted = (uint2*)(wl + 24576);                 // NE uint2
    int*    off    = (int*)(sorted + NE);                  // NN+1
    int*    cnt    = off + NN + 1;                         // NN
    int*    cur    = cnt + NN;                             // NN
    int*    bsum   = cur + NN;                             // NBUK
    int*    bbase  = bsum + NBUK;                          // NBUK+1
    uintptr_t xp = ((uintptr_t)(bbase + NBUK + 1) + 15) & ~(uintptr_t)15;
    _Float16* xh = (_Float16*)xp;                          // NN*64 fp16

    hipMemsetAsync(cnt, 0, NN * sizeof(int), stream);

    k01 <<<487 + CNT_BLKS, 256, 0, stream>>>(Wp, Wn, w1, w2, cf, wh, wl,
                                             x, attw, es1, xh, ei, cnt);
    kA  <<<NBUK, 128, 0, stream>>>(cnt, bsum);
    kB  <<<1, 1024, 0, stream>>>(bsum, bbase);
    kC  <<<NBUK, 128, 0, stream>>>(cnt, bbase, off, cur);
    kS  <<<CNT_BLKS, 256, 0, stream>>>(ei, rf, es1, cur, sorted);
    k4a_agg <<<NN/4, 256, 0, stream>>>(sorted, off, xh, uv);
    k4b5    <<<(NN+127)/128, 512, 0, stream>>>(uv, wh, wl, x, g1, be1, b1, b2, g2, be2, out);
}

// Round 8
// 305.973 us; speedup vs baseline: 1.2348x; 1.2348x over previous
//
#include <hip/hip_runtime.h>
#include <math.h>

#define NN 100000
#define NE 1600000
#define DD 64
#define NBUK 782          // ceil(NN/128), bucket = dst>>7
#define TILE 2048         // partition tile (782 blocks -> ~3/CU; r6's 8192 gave 7% occ)
#define NTB ((NE + TILE - 1) / TILE)
#define BSTRIDE 3072      // padded per-bucket capacity in tmp (mean 2046, >20 sigma)
#define SCAP 3072         // kscat2 LDS output staging capacity

typedef __attribute__((ext_vector_type(8))) short short8;
typedef __attribute__((ext_vector_type(4))) float f32x4;
typedef __attribute__((ext_vector_type(4))) _Float16 h4;
typedef __attribute__((ext_vector_type(2))) _Float16 f16x2;

__device__ __forceinline__ float gelu_exact(float v) {
    return 0.5f * v * (1.0f + erff(v * 0.7071067811865475f));
}

__device__ __forceinline__ unsigned short f2bf(float f) {   // RNE
    unsigned u = __float_as_uint(f);
    return (unsigned short)((u + 0x7FFFu + ((u >> 16) & 1u)) >> 16);
}
__device__ __forceinline__ float bf2f(unsigned short h) {
    return __uint_as_float((unsigned)h << 16);
}
__device__ __forceinline__ void split8v(float4 x0, float4 x1, short8& hi, short8& lo) {
    float v[8] = {x0.x, x0.y, x0.z, x0.w, x1.x, x1.y, x1.z, x1.w};
    #pragma unroll
    for (int i = 0; i < 8; ++i) {
        unsigned short h = f2bf(v[i]);
        hi[i] = (short)h;
        lo[i] = (short)f2bf(v[i] - bf2f(h));
    }
}
// read 8 consecutive floats (k0 = u0*4) from a unit-XOR-swizzled 16x64 tile
__device__ __forceinline__ void lds_frag(const float* g, int row, int u0, int s,
                                         short8& hi, short8& lo) {
    float4 p0 = *(const float4*)&g[row * 64 + ((u0 ^ s) << 2)];
    float4 p1 = *(const float4*)&g[row * 64 + (((u0 + 1) ^ s) << 2)];
    split8v(p0, p1, hi, lo);
}

__device__ __forceinline__ f16x2 as_f16x2(unsigned int u) {
    union { unsigned int x; f16x2 h; } c; c.x = u; return c.h;
}
__device__ __forceinline__ unsigned short h_as_us(_Float16 h) {
    union { _Float16 h; unsigned short u; } c; c.h = h; return c.u;
}
__device__ __forceinline__ float us_as_f(unsigned short u) {
    union { unsigned short u; _Float16 h; } c; c.u = u; return (float)c.h;
}

// K01: fused weight-prep (blocks <96) + attention projection / fp16-x copy
__global__ __launch_bounds__(256) void k01(
    const float* __restrict__ Wp, const float* __restrict__ Wn,
    const float* __restrict__ w1, const float* __restrict__ w2,
    const float* __restrict__ cf,
    unsigned short* __restrict__ wh, unsigned short* __restrict__ wl,
    const float* __restrict__ x, const float* __restrict__ attw,
    float* __restrict__ es1, _Float16* __restrict__ xh)
{
    int bid = blockIdx.x;
    if (bid < 96) {
        int t = bid * 256 + threadIdx.x;   // 24576 total
        float alpha = 1.0f / (1.0f + __expf(-cf[0]));
        float beta  = 1.0f - alpha;
        float v;
        if (t < 8192) {
            int d = t >> 7, k = t & 127;
            v = (k < 64) ? alpha * Wp[d * 64 + k] : beta * Wn[d * 64 + (k - 64)];
        } else if (t < 16384) {
            v = w1[t - 8192];
        } else {
            v = w2[t - 16384];
        }
        unsigned short h = f2bf(v);
        wh[t] = h;
        wl[t] = f2bf(v - bf2f(h));
    } else {
        int n = (bid - 96) * 256 + threadIdx.x;
        if (n >= NN) return;
        const float4* x4 = (const float4*)(x + (size_t)n * DD);
        float a = 0.f;
        #pragma unroll
        for (int i = 0; i < DD/4; ++i) {
            float4 v = x4[i];
            a += v.x*attw[4*i+0] + v.y*attw[4*i+1] + v.z*attw[4*i+2] + v.w*attw[4*i+3];
            h4 hv = {(_Float16)v.x, (_Float16)v.y, (_Float16)v.z, (_Float16)v.w};
            *(h4*)(xh + (size_t)n * DD + 4*i) = hv;
        }
        es1[n] = __expf(a);
    }
}

// KBS: single-block exclusive scan of 782 bucket counts -> bbase
__global__ __launch_bounds__(1024) void ks_bscan(
    const int* __restrict__ bcount, int* __restrict__ bbase)
{
    __shared__ int sa[1024], sb[1024];
    int t = threadIdx.x;
    int v = (t < NBUK) ? bcount[t] : 0;
    sa[t] = v;
    __syncthreads();
    int* s = sa; int* d = sb;
    #pragma unroll
    for (int o = 1; o < 1024; o <<= 1) {
        d[t] = s[t] + ((t >= o) ? s[t - o] : 0);
        __syncthreads();
        int* tmp = s; s = d; d = tmp;
    }
    if (t < NBUK) bbase[t] = s[t] - v;
    if (t == 0) bbase[NBUK] = NE;
}

// KSCAT1: tiled coarse partition into PADDED buckets (stride BSTRIDE).
// TILE=2048 -> 782 blocks (~3/CU) for latency hiding (r6's 8192 -> 7% occ, 64us).
// Packs {src | (dst&127)<<17, fp16x2(es, es*rf)} so downstream never touches
// es1/rf again.
__global__ __launch_bounds__(256) void kscat1(
    const int* __restrict__ ei, const float* __restrict__ rf,
    const float* __restrict__ es1,
    int* __restrict__ bcount, uint2* __restrict__ tmp)
{
    __shared__ int hist[NBUK];
    __shared__ int gbase[NBUK];
    for (int i = threadIdx.x; i < NBUK; i += 256) hist[i] = 0;
    __syncthreads();
    int base = blockIdx.x * TILE;
    int end  = min(base + TILE, NE);
    for (int e = base + threadIdx.x; e < end; e += 256)
        atomicAdd(&hist[ei[NE + e] >> 7], 1);
    __syncthreads();
    for (int i = threadIdx.x; i < NBUK; i += 256) {
        int c = hist[i];
        gbase[i] = c ? (i * BSTRIDE + atomicAdd(bcount + i, c)) : 0;
        hist[i] = 0;                      // reuse as ticket counter
    }
    __syncthreads();
    for (int e = base + threadIdx.x; e < end; e += 256) {
        int src = ei[e];
        int dst = ei[NE + e];
        float es = es1[src];
        float ef = es * rf[e];
        unsigned packed = (unsigned)h_as_us((_Float16)es)
                        | ((unsigned)h_as_us((_Float16)ef) << 16);
        int b = dst >> 7;
        int t = atomicAdd(&hist[b], 1);
        tmp[gbase[b] + t] =
            make_uint2((unsigned)src | ((unsigned)(dst & 127) << 17), packed);
    }
}

// KSCAT2: block-per-bucket fine sort with LDS-staged coalesced output.
__global__ __launch_bounds__(256) void kscat2(
    const uint2* __restrict__ tmp, const int* __restrict__ bcount,
    const int* __restrict__ bbase,
    int* __restrict__ off, uint2* __restrict__ sorted)
{
    __shared__ int hist[128], scn[128], tick[128];
    __shared__ uint2 obuf[SCAP];
    int b   = blockIdx.x;
    int tid = threadIdx.x;
    int si = b * BSTRIDE;        // input (padded tmp)
    int so = bbase[b];           // output (dense sorted)
    int m  = bcount[b];

    if (tid < 128) { hist[tid] = 0; tick[tid] = 0; }
    __syncthreads();

    for (int i = tid; i < m; i += 256)
        atomicAdd(&hist[tmp[si + i].x >> 17], 1);
    __syncthreads();

    if (tid < 128) scn[tid] = hist[tid];
    __syncthreads();
    #pragma unroll
    for (int o = 1; o < 128; o <<= 1) {
        int v = (tid < 128 && tid >= o) ? scn[tid - o] : 0;
        __syncthreads();
        if (tid < 128) scn[tid] += v;
        __syncthreads();
    }

    int nb0 = b * 128;
    if (tid < 128 && nb0 + tid < NN) off[nb0 + tid] = so + scn[tid] - hist[tid];
    if (b == NBUK - 1 && tid == 0) off[NN] = NE;
    __syncthreads();

    for (int i = tid; i < m; i += 256) {
        uint2 pr = tmp[si + i];
        int l = pr.x >> 17;
        int t = atomicAdd(&tick[l], 1);
        int lp = (scn[l] - hist[l]) + t;
        uint2 val = make_uint2(pr.x & 0x1FFFFu, pr.y);
        if (lp < SCAP) obuf[lp] = val;
        else sorted[so + lp] = val;      // statistically never (m <= ~2300)
    }
    __syncthreads();
    int mm = min(m, SCAP);
    for (int i = tid; i < mm; i += 256)
        sorted[so + i] = obuf[i];
}

// K4A v3 (kept from r7): wave-per-node; wave-UNIFORM edge stream (readfirstlane
// bounds -> s_load, no broadcasts); v_dot2_f32_f16 math; fp16 x-gathers.
__global__ __launch_bounds__(256) void k4a_agg(
    const uint2* __restrict__ sorted, const int* __restrict__ off,
    const _Float16* __restrict__ xh, float* __restrict__ uv)
{
    int lane = threadIdx.x & 63;
    int n = blockIdx.x * 4 + (threadIdx.x >> 6);
    int r0 = __builtin_amdgcn_readfirstlane(off[n]);
    int r1 = __builtin_amdgcn_readfirstlane(off[n + 1]);
    const unsigned short* xs = (const unsigned short*)xh;

    float den = 0.f, u = 0.f, v = 0.f;
    const unsigned ONES = 0x3C003C00u;   // fp16x2 {1,1}
    int j = r0;
    for (; j + 8 <= r1; j += 8) {
        uint2 p[8];
        #pragma unroll
        for (int t = 0; t < 8; ++t) p[t] = sorted[j + t];
        unsigned xv[4];
        #pragma unroll
        for (int q = 0; q < 4; ++q) {
            unsigned a0 = xs[(size_t)p[2*q].x   * DD + lane];
            unsigned a1 = xs[(size_t)p[2*q+1].x * DD + lane];
            xv[q] = a0 | (a1 << 16);
        }
        #pragma unroll
        for (int q = 0; q < 4; ++q) {
            unsigned y0 = p[2*q].y, y1 = p[2*q+1].y;
            unsigned e2 = (y0 & 0xFFFFu) | (y1 << 16);
            unsigned f2 = (y0 >> 16) | (y1 & 0xFFFF0000u);
            v   = __builtin_amdgcn_fdot2(as_f16x2(xv[q]), as_f16x2(e2), v, false);
            u   = __builtin_amdgcn_fdot2(as_f16x2(xv[q]), as_f16x2(f2), u, false);
            den = __builtin_amdgcn_fdot2(as_f16x2(e2), as_f16x2(ONES), den, false);
        }
    }
    for (; j + 2 <= r1; j += 2) {
        uint2 p0 = sorted[j], p1 = sorted[j + 1];
        unsigned a0 = xs[(size_t)p0.x * DD + lane];
        unsigned a1 = xs[(size_t)p1.x * DD + lane];
        unsigned xv = a0 | (a1 << 16);
        unsigned e2 = (p0.y & 0xFFFFu) | (p1.y << 16);
        unsigned f2 = (p0.y >> 16) | (p1.y & 0xFFFF0000u);
        v   = __builtin_amdgcn_fdot2(as_f16x2(xv), as_f16x2(e2), v, false);
        u   = __builtin_amdgcn_fdot2(as_f16x2(xv), as_f16x2(f2), u, false);
        den = __builtin_amdgcn_fdot2(as_f16x2(e2), as_f16x2(ONES), den, false);
    }
    if (j < r1) {
        uint2 p0 = sorted[j];
        float xvf = us_as_f((unsigned short)xs[(size_t)p0.x * DD + lane]);
        float e = us_as_f((unsigned short)(p0.y & 0xFFFFu));
        float f = us_as_f((unsigned short)(p0.y >> 16));
        den += e; v += e * xvf; u += f * xvf;
    }
    float inv = (r1 > r0) ? 1.f / den : 0.f;
    uv[(size_t)n * 128 + lane]      = u * inv;
    uv[(size_t)n * 128 + 64 + lane] = v * inv;
}

// K4B5 (unchanged): 512 threads / 8 waves / 128 nodes per block.
__global__ __launch_bounds__(512, 4) void k4b5(
    const float* __restrict__ uv,
    const unsigned short* __restrict__ wh, const unsigned short* __restrict__ wl,
    const float* __restrict__ x,
    const float* __restrict__ g1, const float* __restrict__ be1,
    const float* __restrict__ bb1, const float* __restrict__ bb2,
    const float* __restrict__ g2, const float* __restrict__ be2,
    float* __restrict__ out)
{
    __shared__ unsigned short WH[8192], WL[8192];   // Bmix 64x128 / w1 128x64
    __shared__ unsigned short W2H[4096], W2L[4096]; // w2 k-half 64x64
    __shared__ float Gt[8][1024];                   // per-wave 16x64 (h / Ga / Gb)

    int tid  = threadIdx.x;
    int lane = tid & 63;
    int wv   = tid >> 6;
    int quad = lane >> 4, l16 = lane & 15;
    int s7   = l16 & 7;
    int nb = blockIdx.x * 128 + wv * 16;
    float* gt = Gt[wv];

    const float4* arow4 = (const float4*)(uv + (size_t)min(nb + l16, NN - 1) * 128);
    float4 av[8];
    #pragma unroll
    for (int ks = 0; ks < 4; ++ks) {
        av[2*ks]   = arow4[ks*8 + quad*2];
        av[2*ks+1] = arow4[ks*8 + quad*2 + 1];
    }
    float xr[4][4];
    #pragma unroll
    for (int r = 0; r < 4; ++r) {
        size_t nld = (size_t)min(nb + quad*4 + r, NN - 1) * 64;
        #pragma unroll
        for (int nt = 0; nt < 4; ++nt) xr[r][nt] = x[nld + nt*16 + l16];
    }

    #pragma unroll
    for (int k = 0; k < 2; ++k) {
        int i = tid + k*512;                 // 0..1023
        int row = i >> 4, u = i & 15;
        int up = u ^ (row & 7);
        *(short8*)&WH[row*128 + up*8] = *(const short8*)&wh[i*8];
        *(short8*)&WL[row*128 + up*8] = *(const short8*)&wl[i*8];
    }
    __syncthreads();

    f32x4 acc0[4] = {};
    #pragma unroll
    for (int ks = 0; ks < 4; ++ks) {
        short8 ah, al;
        split8v(av[2*ks], av[2*ks+1], ah, al);
        int u0 = 4*ks + quad;
        #pragma unroll
        for (int nt = 0; nt < 4; ++nt) {
            int wo = (nt*16 + l16)*128 + (u0 ^ s7)*8;
            short8 bh = *(const short8*)&WH[wo];
            short8 bl = *(const short8*)&WL[wo];
            acc0[nt] = __builtin_amdgcn_mfma_f32_16x16x32_bf16(ah, bh, acc0[nt], 0, 0, 0);
            acc0[nt] = __builtin_amdgcn_mfma_f32_16x16x32_bf16(al, bh, acc0[nt], 0, 0, 0);
            acc0[nt] = __builtin_amdgcn_mfma_f32_16x16x32_bf16(ah, bl, acc0[nt], 0, 0, 0);
        }
    }

    float hn[4][4];
    #pragma unroll
    for (int r = 0; r < 4; ++r) {
        float hv[4];
        #pragma unroll
        for (int nt = 0; nt < 4; ++nt)
            hv[nt] = gelu_exact(acc0[nt][r]) + xr[r][nt];
        float s = hv[0] + hv[1] + hv[2] + hv[3];
        #pragma unroll
        for (int o = 1; o < 16; o <<= 1) s += __shfl_xor(s, o);
        float mu = s * (1.0f/64.0f);
        float q = 0.f;
        #pragma unroll
        for (int nt = 0; nt < 4; ++nt) { float t = hv[nt] - mu; q += t*t; }
        #pragma unroll
        for (int o = 1; o < 16; o <<= 1) q += __shfl_xor(q, o);
        float rs = rsqrtf(q * (1.0f/64.0f) + 1e-5f);
        int row = quad*4 + r;
        #pragma unroll
        for (int nt = 0; nt < 4; ++nt) {
            int c = nt*16 + l16;
            float h = (hv[nt] - mu) * rs * g1[c] + be1[c];
            hn[r][nt] = h;
            int u = c >> 2;
            gt[row*64 + ((u ^ (row & 7)) << 2) + (c & 3)] = h;
        }
    }
    __syncthreads();    // all waves done reading Bmix

    #pragma unroll
    for (int k = 0; k < 2; ++k) {
        int i = tid + k*512;                 // 0..1023
        int row = i >> 3, u = i & 7;
        int up = u ^ (row & 7);
        *(short8*)&WH[row*64 + up*8] = *(const short8*)&wh[8192 + i*8];
        *(short8*)&WL[row*64 + up*8] = *(const short8*)&wl[8192 + i*8];
    }
    {
        int row = tid >> 3, u = tid & 7;     // 512 units
        int up = u ^ (row & 7);
        *(short8*)&W2H[row*64 + up*8] = *(const short8*)&wh[16384 + row*128 + u*8];
        *(short8*)&W2L[row*64 + up*8] = *(const short8*)&wl[16384 + row*128 + u*8];
    }
    __syncthreads();

    short8 ah1[2], al1[2];
    #pragma unroll
    for (int ks = 0; ks < 2; ++ks)
        lds_frag(gt, l16, 8*ks + 2*quad, s7, ah1[ks], al1[ks]);

    f32x4 acc2[4] = {};
    #pragma unroll
    for (int half = 0; half < 2; ++half) {
        f32x4 a1[4] = {};
        #pragma unroll
        for (int ks = 0; ks < 2; ++ks) {
            int u0 = 4*ks + quad;
            #pragma unroll
            for (int t = 0; t < 4; ++t) {
                int row = half*64 + t*16 + l16;
                int wo = row*64 + ((u0 ^ s7))*8;
                short8 bh = *(const short8*)&WH[wo];
                short8 bl = *(const short8*)&WL[wo];
                a1[t] = __builtin_amdgcn_mfma_f32_16x16x32_bf16(ah1[ks], bh, a1[t], 0, 0, 0);
                a1[t] = __builtin_amdgcn_mfma_f32_16x16x32_bf16(al1[ks], bh, a1[t], 0, 0, 0);
                a1[t] = __builtin_amdgcn_mfma_f32_16x16x32_bf16(ah1[ks], bl, a1[t], 0, 0, 0);
            }
        }
        #pragma unroll
        for (int t = 0; t < 4; ++t) {
            float b1v = bb1[half*64 + t*16 + l16];
            #pragma unroll
            for (int r = 0; r < 4; ++r) {
                int row = quad*4 + r;
                int c = t*16 + l16;
                int u = c >> 2;
                gt[row*64 + ((u ^ (row & 7)) << 2) + (c & 3)] = gelu_exact(a1[t][r] + b1v);
            }
        }
        #pragma unroll
        for (int ks2 = 0; ks2 < 2; ++ks2) {
            short8 ah2, al2;
            lds_frag(gt, l16, 8*ks2 + 2*quad, s7, ah2, al2);
            int u0 = 4*ks2 + quad;
            #pragma unroll
            for (int nt2 = 0; nt2 < 4; ++nt2) {
                int wo = (nt2*16 + l16)*64 + (u0 ^ s7)*8;
                short8 bh = *(const short8*)&W2H[wo];
                short8 bl = *(const short8*)&W2L[wo];
                acc2[nt2] = __builtin_amdgcn_mfma_f32_16x16x32_bf16(ah2, bh, acc2[nt2], 0, 0, 0);
                acc2[nt2] = __builtin_amdgcn_mfma_f32_16x16x32_bf16(al2, bh, acc2[nt2], 0, 0, 0);
                acc2[nt2] = __builtin_amdgcn_mfma_f32_16x16x32_bf16(ah2, bl, acc2[nt2], 0, 0, 0);
            }
        }
        if (half == 0) {
            __syncthreads();   // all waves done with w2 half A
            int row = tid >> 3, u = tid & 7;
            int up = u ^ (row & 7);
            *(short8*)&W2H[row*64 + up*8] = *(const short8*)&wh[16384 + row*128 + 64 + u*8];
            *(short8*)&W2L[row*64 + up*8] = *(const short8*)&wl[16384 + row*128 + 64 + u*8];
            __syncthreads();
        }
    }

    #pragma unroll
    for (int r = 0; r < 4; ++r) {
        int n = nb + quad * 4 + r;
        float mv[4];
        #pragma unroll
        for (int nt = 0; nt < 4; ++nt)
            mv[nt] = acc2[nt][r] + hn[r][nt] + bb2[nt*16 + l16];
        float s = mv[0] + mv[1] + mv[2] + mv[3];
        #pragma unroll
        for (int o = 1; o < 16; o <<= 1) s += __shfl_xor(s, o);
        float mu = s * (1.0f/64.0f);
        float q = 0.f;
        #pragma unroll
        for (int nt = 0; nt < 4; ++nt) { float t = mv[nt] - mu; q += t*t; }
        #pragma unroll
        for (int o = 1; o < 16; o <<= 1) q += __shfl_xor(q, o);
        float rs = rsqrtf(q * (1.0f/64.0f) + 1e-5f);
        if (n < NN) {
            #pragma unroll
            for (int nt = 0; nt < 4; ++nt) {
                int c = nt*16 + l16;
                out[(size_t)n * 64 + c] = (mv[nt] - mu) * rs * g2[c] + be2[c];
            }
        }
    }
}

extern "C" void kernel_launch(void* const* d_in, const int* in_sizes, int n_in,
                              void* d_out, int out_size, void* d_ws, size_t ws_size,
                              hipStream_t stream) {
    const float* x    = (const float*)d_in[0];
    const int*   ei   = (const int*)d_in[1];
    const float* rf   = (const float*)d_in[2];
    const float* Wp   = (const float*)d_in[3];
    const float* Wn   = (const float*)d_in[4];
    const float* attw = (const float*)d_in[5];
    const float* cf   = (const float*)d_in[6];
    const float* w1   = (const float*)d_in[7];
    const float* b1   = (const float*)d_in[8];
    const float* w2   = (const float*)d_in[9];
    const float* b2   = (const float*)d_in[10];
    const float* g1   = (const float*)d_in[11];
    const float* be1  = (const float*)d_in[12];
    const float* g2   = (const float*)d_in[13];
    const float* be2  = (const float*)d_in[14];
    float* out = (float*)d_out;

    float* ws = (float*)d_ws;
    float*  es1    = ws;                                   // NN
    float*  uv     = es1 + NN;                             // NN*128
    unsigned short* wh = (unsigned short*)(uv + (size_t)NN * 128);   // 24576 u16
    unsigned short* wl = wh + 24576;                                 // 24576 u16
    uint2*  sorted = (uint2*)(wl + 24576);                 // NE uint2
    int*    off    = (int*)(sorted + NE);                  // NN+1
    int*    bcount = off + NN + 1;                         // NBUK
    int*    bbase  = bcount + NBUK;                        // NBUK+1
    uintptr_t xp = ((uintptr_t)(bbase + NBUK + 1) + 15) & ~(uintptr_t)15;
    _Float16* xh = (_Float16*)xp;                          // NN*64 fp16
    uint2*  tmp    = (uint2*)uv;                           // padded NBUK*BSTRIDE uint2 (19.2MB < 51.2MB)

    hipMemsetAsync(bcount, 0, NBUK * sizeof(int), stream);

    int k01grid = 96 + (NN + 255) / 256;
    k01       <<<k01grid, 256, 0, stream>>>(Wp, Wn, w1, w2, cf, wh, wl, x, attw, es1, xh);
    kscat1    <<<NTB, 256, 0, stream>>>(ei, rf, es1, bcount, tmp);
    ks_bscan  <<<1, 1024, 0, stream>>>(bcount, bbase);
    kscat2    <<<NBUK, 256, 0, stream>>>(tmp, bcount, bbase, off, sorted);
    k4a_agg   <<<NN/4, 256, 0, stream>>>(sorted, off, xh, uv);
    k4b5      <<<(NN+127)/128, 512, 0, stream>>>(uv, wh, wl, x, g1, be1, b1, b2, g2, be2, out);
}

// Round 9
// 263.296 us; speedup vs baseline: 1.4349x; 1.1621x over previous
//
#include <hip/hip_runtime.h>
#include <math.h>

#define NN 100000
#define NE 1600000
#define DD 64
#define NBUK 782          // ceil(NN/128), bucket = dst>>7
#define TILE 8192         // long runs (10.5 edges) -> low write amplification
#define NTB ((NE + TILE - 1) / TILE)   // 196 partition blocks
#define NWB 96            // weight-prep blocks
#define NPB ((NN + 255) / 256)         // 391 projection blocks
#define BSTRIDE 3072      // padded per-bucket capacity in tmp
#define SCAP 3072         // kscat2 LDS output staging capacity

typedef __attribute__((ext_vector_type(8))) short short8;
typedef __attribute__((ext_vector_type(4))) float f32x4;
typedef __attribute__((ext_vector_type(4))) _Float16 h4;
typedef __attribute__((ext_vector_type(2))) _Float16 f16x2;

__device__ __forceinline__ float gelu_exact(float v) {
    return 0.5f * v * (1.0f + erff(v * 0.7071067811865475f));
}

__device__ __forceinline__ unsigned short f2bf(float f) {   // RNE
    unsigned u = __float_as_uint(f);
    return (unsigned short)((u + 0x7FFFu + ((u >> 16) & 1u)) >> 16);
}
__device__ __forceinline__ float bf2f(unsigned short h) {
    return __uint_as_float((unsigned)h << 16);
}
__device__ __forceinline__ void split8v(float4 x0, float4 x1, short8& hi, short8& lo) {
    float v[8] = {x0.x, x0.y, x0.z, x0.w, x1.x, x1.y, x1.z, x1.w};
    #pragma unroll
    for (int i = 0; i < 8; ++i) {
        unsigned short h = f2bf(v[i]);
        hi[i] = (short)h;
        lo[i] = (short)f2bf(v[i] - bf2f(h));
    }
}
// read 8 consecutive floats (k0 = u0*4) from a unit-XOR-swizzled 16x64 tile
__device__ __forceinline__ void lds_frag(const float* g, int row, int u0, int s,
                                         short8& hi, short8& lo) {
    float4 p0 = *(const float4*)&g[row * 64 + ((u0 ^ s) << 2)];
    float4 p1 = *(const float4*)&g[row * 64 + (((u0 + 1) ^ s) << 2)];
    split8v(p0, p1, hi, lo);
}

__device__ __forceinline__ f16x2 as_f16x2(unsigned int u) {
    union { unsigned int x; f16x2 h; } c; c.x = u; return c.h;
}
__device__ __forceinline__ unsigned short h_as_us(_Float16 h) {
    union { _Float16 h; unsigned short u; } c; c.h = h; return c.u;
}
__device__ __forceinline__ float us_as_f(unsigned short u) {
    union { unsigned short u; _Float16 h; } c; c.u = u; return (float)c.h;
}

// KFRONT: three independent jobs in ONE grid for co-residency latency hiding.
//   blocks [0, NTB): edge partition (the latency-bound scatter — its stalls
//                    are hidden by the other blocks' VALU/streaming work)
//   blocks [NTB, NTB+NWB): bf16 hi/lo weight prep
//   blocks [NTB+NWB, ...): attention projection + es1 + fp16 x copy
__global__ __launch_bounds__(256) void kfront(
    const int* __restrict__ ei, const float* __restrict__ rf,
    int* __restrict__ bcount, uint2* __restrict__ tmp,
    const float* __restrict__ Wp, const float* __restrict__ Wn,
    const float* __restrict__ w1, const float* __restrict__ w2,
    const float* __restrict__ cf,
    unsigned short* __restrict__ wh, unsigned short* __restrict__ wl,
    const float* __restrict__ x, const float* __restrict__ attw,
    float* __restrict__ es1, _Float16* __restrict__ xh)
{
    __shared__ int hist[NBUK];
    __shared__ int gbase[NBUK];
    int bid = blockIdx.x;
    int tid = threadIdx.x;

    if (bid < NTB) {
        // ---- partition tile ----
        for (int i = tid; i < NBUK; i += 256) hist[i] = 0;
        __syncthreads();
        int base = bid * TILE;
        int end  = min(base + TILE, NE);
        for (int e = base + tid; e < end; e += 256)
            atomicAdd(&hist[ei[NE + e] >> 7], 1);
        __syncthreads();
        for (int i = tid; i < NBUK; i += 256) {
            int c = hist[i];
            gbase[i] = c ? (i * BSTRIDE + atomicAdd(bcount + i, c)) : 0;
            hist[i] = 0;                  // reuse as ticket counter
        }
        __syncthreads();
        // batched scatter: 4 edges' loads in flight before the atomic+store phase
        for (int e0 = base + tid; e0 < end; e0 += 256 * 4) {
            int srcs[4], dsts[4]; unsigned rfs[4];
            #pragma unroll
            for (int q = 0; q < 4; ++q) {
                int e = e0 + q * 256;
                if (e < end) {
                    srcs[q] = ei[e];
                    dsts[q] = ei[NE + e];
                    rfs[q]  = __float_as_uint(rf[e]);
                }
            }
            #pragma unroll
            for (int q = 0; q < 4; ++q) {
                int e = e0 + q * 256;
                if (e < end) {
                    int b = dsts[q] >> 7;
                    int t = atomicAdd(&hist[b], 1);
                    tmp[gbase[b] + t] = make_uint2(
                        (unsigned)srcs[q] | ((unsigned)(dsts[q] & 127) << 17),
                        rfs[q]);
                }
            }
        }
    } else if (bid < NTB + NWB) {
        // ---- weight prep ----
        int t = (bid - NTB) * 256 + tid;   // 24576 total
        float alpha = 1.0f / (1.0f + __expf(-cf[0]));
        float beta  = 1.0f - alpha;
        float v;
        if (t < 8192) {
            int d = t >> 7, k = t & 127;
            v = (k < 64) ? alpha * Wp[d * 64 + k] : beta * Wn[d * 64 + (k - 64)];
        } else if (t < 16384) {
            v = w1[t - 8192];
        } else {
            v = w2[t - 16384];
        }
        unsigned short h = f2bf(v);
        wh[t] = h;
        wl[t] = f2bf(v - bf2f(h));
    } else {
        // ---- attention projection + fp16 x ----
        int n = (bid - NTB - NWB) * 256 + tid;
        if (n >= NN) return;
        const float4* x4 = (const float4*)(x + (size_t)n * DD);
        float a = 0.f;
        #pragma unroll
        for (int i = 0; i < DD/4; ++i) {
            float4 v = x4[i];
            a += v.x*attw[4*i+0] + v.y*attw[4*i+1] + v.z*attw[4*i+2] + v.w*attw[4*i+3];
            h4 hv = {(_Float16)v.x, (_Float16)v.y, (_Float16)v.z, (_Float16)v.w};
            *(h4*)(xh + (size_t)n * DD + 4*i) = hv;
        }
        es1[n] = __expf(a);
    }
}

// KBS: single-block exclusive scan of 782 bucket counts -> bbase
__global__ __launch_bounds__(1024) void ks_bscan(
    const int* __restrict__ bcount, int* __restrict__ bbase)
{
    __shared__ int sa[1024], sb[1024];
    int t = threadIdx.x;
    int v = (t < NBUK) ? bcount[t] : 0;
    sa[t] = v;
    __syncthreads();
    int* s = sa; int* d = sb;
    #pragma unroll
    for (int o = 1; o < 1024; o <<= 1) {
        d[t] = s[t] + ((t >= o) ? s[t - o] : 0);
        __syncthreads();
        int* tmp = s; s = d; d = tmp;
    }
    if (t < NBUK) bbase[t] = s[t] - v;
    if (t == 0) bbase[NBUK] = NE;
}

// KSCAT2: block-per-bucket fine sort; gathers es1[src], packs fp16x2(es, es*rf);
// LDS-staged coalesced output.
__global__ __launch_bounds__(256) void kscat2(
    const uint2* __restrict__ tmp, const int* __restrict__ bcount,
    const int* __restrict__ bbase, const float* __restrict__ es1,
    int* __restrict__ off, uint2* __restrict__ sorted)
{
    __shared__ int hist[128], scn[128], tick[128];
    __shared__ uint2 obuf[SCAP];
    int b   = blockIdx.x;
    int tid = threadIdx.x;
    int si = b * BSTRIDE;        // input (padded tmp)
    int so = bbase[b];           // output (dense sorted)
    int m  = bcount[b];

    if (tid < 128) { hist[tid] = 0; tick[tid] = 0; }
    __syncthreads();

    for (int i = tid; i < m; i += 256)
        atomicAdd(&hist[tmp[si + i].x >> 17], 1);
    __syncthreads();

    if (tid < 128) scn[tid] = hist[tid];
    __syncthreads();
    #pragma unroll
    for (int o = 1; o < 128; o <<= 1) {
        int v = (tid < 128 && tid >= o) ? scn[tid - o] : 0;
        __syncthreads();
        if (tid < 128) scn[tid] += v;
        __syncthreads();
    }

    int nb0 = b * 128;
    if (tid < 128 && nb0 + tid < NN) off[nb0 + tid] = so + scn[tid] - hist[tid];
    if (b == NBUK - 1 && tid == 0) off[NN] = NE;
    __syncthreads();

    for (int i = tid; i < m; i += 256) {
        uint2 pr = tmp[si + i];
        int l   = pr.x >> 17;
        int src = pr.x & 0x1FFFF;
        float es = es1[src];
        float ef = es * __uint_as_float(pr.y);
        unsigned packed = (unsigned)h_as_us((_Float16)es)
                        | ((unsigned)h_as_us((_Float16)ef) << 16);
        int t = atomicAdd(&tick[l], 1);
        int lp = (scn[l] - hist[l]) + t;
        uint2 val = make_uint2((unsigned)src, packed);
        if (lp < SCAP) obuf[lp] = val;
        else sorted[so + lp] = val;      // statistically never (m <= ~2300)
    }
    __syncthreads();
    int mm = min(m, SCAP);
    for (int i = tid; i < mm; i += 256)
        sorted[so + i] = obuf[i];
}

// K4A v3: wave-per-node; wave-UNIFORM edge stream (readfirstlane bounds ->
// s_load, no broadcasts); v_dot2_f32_f16 math; fp16 x-gathers.
__global__ __launch_bounds__(256) void k4a_agg(
    const uint2* __restrict__ sorted, const int* __restrict__ off,
    const _Float16* __restrict__ xh, float* __restrict__ uv)
{
    int lane = threadIdx.x & 63;
    int n = blockIdx.x * 4 + (threadIdx.x >> 6);
    int r0 = __builtin_amdgcn_readfirstlane(off[n]);
    int r1 = __builtin_amdgcn_readfirstlane(off[n + 1]);
    const unsigned short* xs = (const unsigned short*)xh;

    float den = 0.f, u = 0.f, v = 0.f;
    const unsigned ONES = 0x3C003C00u;   // fp16x2 {1,1}
    int j = r0;
    for (; j + 8 <= r1; j += 8) {
        uint2 p[8];
        #pragma unroll
        for (int t = 0; t < 8; ++t) p[t] = sorted[j + t];
        unsigned xv[4];
        #pragma unroll
        for (int q = 0; q < 4; ++q) {
            unsigned a0 = xs[(size_t)p[2*q].x   * DD + lane];
            unsigned a1 = xs[(size_t)p[2*q+1].x * DD + lane];
            xv[q] = a0 | (a1 << 16);
        }
        #pragma unroll
        for (int q = 0; q < 4; ++q) {
            unsigned y0 = p[2*q].y, y1 = p[2*q+1].y;
            unsigned e2 = (y0 & 0xFFFFu) | (y1 << 16);
            unsigned f2 = (y0 >> 16) | (y1 & 0xFFFF0000u);
            v   = __builtin_amdgcn_fdot2(as_f16x2(xv[q]), as_f16x2(e2), v, false);
            u   = __builtin_amdgcn_fdot2(as_f16x2(xv[q]), as_f16x2(f2), u, false);
            den = __builtin_amdgcn_fdot2(as_f16x2(e2), as_f16x2(ONES), den, false);
        }
    }
    for (; j + 2 <= r1; j += 2) {
        uint2 p0 = sorted[j], p1 = sorted[j + 1];
        unsigned a0 = xs[(size_t)p0.x * DD + lane];
        unsigned a1 = xs[(size_t)p1.x * DD + lane];
        unsigned xv = a0 | (a1 << 16);
        unsigned e2 = (p0.y & 0xFFFFu) | (p1.y << 16);
        unsigned f2 = (p0.y >> 16) | (p1.y & 0xFFFF0000u);
        v   = __builtin_amdgcn_fdot2(as_f16x2(xv), as_f16x2(e2), v, false);
        u   = __builtin_amdgcn_fdot2(as_f16x2(xv), as_f16x2(f2), u, false);
        den = __builtin_amdgcn_fdot2(as_f16x2(e2), as_f16x2(ONES), den, false);
    }
    if (j < r1) {
        uint2 p0 = sorted[j];
        float xvf = us_as_f((unsigned short)xs[(size_t)p0.x * DD + lane]);
        float e = us_as_f((unsigned short)(p0.y & 0xFFFFu));
        float f = us_as_f((unsigned short)(p0.y >> 16));
        den += e; v += e * xvf; u += f * xvf;
    }
    float inv = (r1 > r0) ? 1.f / den : 0.f;
    uv[(size_t)n * 128 + lane]      = u * inv;
    uv[(size_t)n * 128 + 64 + lane] = v * inv;
}

// K4B5 (unchanged): 512 threads / 8 waves / 128 nodes per block.
__global__ __launch_bounds__(512, 4) void k4b5(
    const float* __restrict__ uv,
    const unsigned short* __restrict__ wh, const unsigned short* __restrict__ wl,
    const float* __restrict__ x,
    const float* __restrict__ g1, const float* __restrict__ be1,
    const float* __restrict__ bb1, const float* __restrict__ bb2,
    const float* __restrict__ g2, const float* __restrict__ be2,
    float* __restrict__ out)
{
    __shared__ unsigned short WH[8192], WL[8192];   // Bmix 64x128 / w1 128x64
    __shared__ unsigned short W2H[4096], W2L[4096]; // w2 k-half 64x64
    __shared__ float Gt[8][1024];                   // per-wave 16x64 (h / Ga / Gb)

    int tid  = threadIdx.x;
    int lane = tid & 63;
    int wv   = tid >> 6;
    int quad = lane >> 4, l16 = lane & 15;
    int s7   = l16 & 7;
    int nb = blockIdx.x * 128 + wv * 16;
    float* gt = Gt[wv];

    const float4* arow4 = (const float4*)(uv + (size_t)min(nb + l16, NN - 1) * 128);
    float4 av[8];
    #pragma unroll
    for (int ks = 0; ks < 4; ++ks) {
        av[2*ks]   = arow4[ks*8 + quad*2];
        av[2*ks+1] = arow4[ks*8 + quad*2 + 1];
    }
    float xr[4][4];
    #pragma unroll
    for (int r = 0; r < 4; ++r) {
        size_t nld = (size_t)min(nb + quad*4 + r, NN - 1) * 64;
        #pragma unroll
        for (int nt = 0; nt < 4; ++nt) xr[r][nt] = x[nld + nt*16 + l16];
    }

    #pragma unroll
    for (int k = 0; k < 2; ++k) {
        int i = tid + k*512;                 // 0..1023
        int row = i >> 4, u = i & 15;
        int up = u ^ (row & 7);
        *(short8*)&WH[row*128 + up*8] = *(const short8*)&wh[i*8];
        *(short8*)&WL[row*128 + up*8] = *(const short8*)&wl[i*8];
    }
    __syncthreads();

    f32x4 acc0[4] = {};
    #pragma unroll
    for (int ks = 0; ks < 4; ++ks) {
        short8 ah, al;
        split8v(av[2*ks], av[2*ks+1], ah, al);
        int u0 = 4*ks + quad;
        #pragma unroll
        for (int nt = 0; nt < 4; ++nt) {
            int wo = (nt*16 + l16)*128 + (u0 ^ s7)*8;
            short8 bh = *(const short8*)&WH[wo];
            short8 bl = *(const short8*)&WL[wo];
            acc0[nt] = __builtin_amdgcn_mfma_f32_16x16x32_bf16(ah, bh, acc0[nt], 0, 0, 0);
            acc0[nt] = __builtin_amdgcn_mfma_f32_16x16x32_bf16(al, bh, acc0[nt], 0, 0, 0);
            acc0[nt] = __builtin_amdgcn_mfma_f32_16x16x32_bf16(ah, bl, acc0[nt], 0, 0, 0);
        }
    }

    float hn[4][4];
    #pragma unroll
    for (int r = 0; r < 4; ++r) {
        float hv[4];
        #pragma unroll
        for (int nt = 0; nt < 4; ++nt)
            hv[nt] = gelu_exact(acc0[nt][r]) + xr[r][nt];
        float s = hv[0] + hv[1] + hv[2] + hv[3];
        #pragma unroll
        for (int o = 1; o < 16; o <<= 1) s += __shfl_xor(s, o);
        float mu = s * (1.0f/64.0f);
        float q = 0.f;
        #pragma unroll
        for (int nt = 0; nt < 4; ++nt) { float t = hv[nt] - mu; q += t*t; }
        #pragma unroll
        for (int o = 1; o < 16; o <<= 1) q += __shfl_xor(q, o);
        float rs = rsqrtf(q * (1.0f/64.0f) + 1e-5f);
        int row = quad*4 + r;
        #pragma unroll
        for (int nt = 0; nt < 4; ++nt) {
            int c = nt*16 + l16;
            float h = (hv[nt] - mu) * rs * g1[c] + be1[c];
            hn[r][nt] = h;
            int u = c >> 2;
            gt[row*64 + ((u ^ (row & 7)) << 2) + (c & 3)] = h;
        }
    }
    __syncthreads();    // all waves done reading Bmix

    #pragma unroll
    for (int k = 0; k < 2; ++k) {
        int i = tid + k*512;                 // 0..1023
        int row = i >> 3, u = i & 7;
        int up = u ^ (row & 7);
        *(short8*)&WH[row*64 + up*8] = *(const short8*)&wh[8192 + i*8];
        *(short8*)&WL[row*64 + up*8] = *(const short8*)&wl[8192 + i*8];
    }
    {
        int row = tid >> 3, u = tid & 7;     // 512 units
        int up = u ^ (row & 7);
        *(short8*)&W2H[row*64 + up*8] = *(const short8*)&wh[16384 + row*128 + u*8];
        *(short8*)&W2L[row*64 + up*8] = *(const short8*)&wl[16384 + row*128 + u*8];
    }
    __syncthreads();

    short8 ah1[2], al1[2];
    #pragma unroll
    for (int ks = 0; ks < 2; ++ks)
        lds_frag(gt, l16, 8*ks + 2*quad, s7, ah1[ks], al1[ks]);

    f32x4 acc2[4] = {};
    #pragma unroll
    for (int half = 0; half < 2; ++half) {
        f32x4 a1[4] = {};
        #pragma unroll
        for (int ks = 0; ks < 2; ++ks) {
            int u0 = 4*ks + quad;
            #pragma unroll
            for (int t = 0; t < 4; ++t) {
                int row = half*64 + t*16 + l16;
                int wo = row*64 + ((u0 ^ s7))*8;
                short8 bh = *(const short8*)&WH[wo];
                short8 bl = *(const short8*)&WL[wo];
                a1[t] = __builtin_amdgcn_mfma_f32_16x16x32_bf16(ah1[ks], bh, a1[t], 0, 0, 0);
                a1[t] = __builtin_amdgcn_mfma_f32_16x16x32_bf16(al1[ks], bh, a1[t], 0, 0, 0);
                a1[t] = __builtin_amdgcn_mfma_f32_16x16x32_bf16(ah1[ks], bl, a1[t], 0, 0, 0);
            }
        }
        #pragma unroll
        for (int t = 0; t < 4; ++t) {
            float b1v = bb1[half*64 + t*16 + l16];
            #pragma unroll
            for (int r = 0; r < 4; ++r) {
                int row = quad*4 + r;
                int c = t*16 + l16;
                int u = c >> 2;
                gt[row*64 + ((u ^ (row & 7)) << 2) + (c & 3)] = gelu_exact(a1[t][r] + b1v);
            }
        }
        #pragma unroll
        for (int ks2 = 0; ks2 < 2; ++ks2) {
            short8 ah2, al2;
            lds_frag(gt, l16, 8*ks2 + 2*quad, s7, ah2, al2);
            int u0 = 4*ks2 + quad;
            #pragma unroll
            for (int nt2 = 0; nt2 < 4; ++nt2) {
                int wo = (nt2*16 + l16)*64 + (u0 ^ s7)*8;
                short8 bh = *(const short8*)&W2H[wo];
                short8 bl = *(const short8*)&W2L[wo];
                acc2[nt2] = __builtin_amdgcn_mfma_f32_16x16x32_bf16(ah2, bh, acc2[nt2], 0, 0, 0);
                acc2[nt2] = __builtin_amdgcn_mfma_f32_16x16x32_bf16(al2, bh, acc2[nt2], 0, 0, 0);
                acc2[nt2] = __builtin_amdgcn_mfma_f32_16x16x32_bf16(ah2, bl, acc2[nt2], 0, 0, 0);
            }
        }
        if (half == 0) {
            __syncthreads();   // all waves done with w2 half A
            int row = tid >> 3, u = tid & 7;
            int up = u ^ (row & 7);
            *(short8*)&W2H[row*64 + up*8] = *(const short8*)&wh[16384 + row*128 + 64 + u*8];
            *(short8*)&W2L[row*64 + up*8] = *(const short8*)&wl[16384 + row*128 + 64 + u*8];
            __syncthreads();
        }
    }

    #pragma unroll
    for (int r = 0; r < 4; ++r) {
        int n = nb + quad * 4 + r;
        float mv[4];
        #pragma unroll
        for (int nt = 0; nt < 4; ++nt)
            mv[nt] = acc2[nt][r] + hn[r][nt] + bb2[nt*16 + l16];
        float s = mv[0] + mv[1] + mv[2] + mv[3];
        #pragma unroll
        for (int o = 1; o < 16; o <<= 1) s += __shfl_xor(s, o);
        float mu = s * (1.0f/64.0f);
        float q = 0.f;
        #pragma unroll
        for (int nt = 0; nt < 4; ++nt) { float t = mv[nt] - mu; q += t*t; }
        #pragma unroll
        for (int o = 1; o < 16; o <<= 1) q += __shfl_xor(q, o);
        float rs = rsqrtf(q * (1.0f/64.0f) + 1e-5f);
        if (n < NN) {
            #pragma unroll
            for (int nt = 0; nt < 4; ++nt) {
                int c = nt*16 + l16;
                out[(size_t)n * 64 + c] = (mv[nt] - mu) * rs * g2[c] + be2[c];
            }
        }
    }
}

extern "C" void kernel_launch(void* const* d_in, const int* in_sizes, int n_in,
                              void* d_out, int out_size, void* d_ws, size_t ws_size,
                              hipStream_t stream) {
    const float* x    = (const float*)d_in[0];
    const int*   ei   = (const int*)d_in[1];
    const float* rf   = (const float*)d_in[2];
    const float* Wp   = (const float*)d_in[3];
    const float* Wn   = (const float*)d_in[4];
    const float* attw = (const float*)d_in[5];
    const float* cf   = (const float*)d_in[6];
    const float* w1   = (const float*)d_in[7];
    const float* b1   = (const float*)d_in[8];
    const float* w2   = (const float*)d_in[9];
    const float* b2   = (const float*)d_in[10];
    const float* g1   = (const float*)d_in[11];
    const float* be1  = (const float*)d_in[12];
    const float* g2   = (const float*)d_in[13];
    const float* be2  = (const float*)d_in[14];
    float* out = (float*)d_out;

    float* ws = (float*)d_ws;
    float*  es1    = ws;                                   // NN
    float*  uv     = es1 + NN;                             // NN*128
    unsigned short* wh = (unsigned short*)(uv + (size_t)NN * 128);   // 24576 u16
    unsigned short* wl = wh + 24576;                                 // 24576 u16
    uint2*  sorted = (uint2*)(wl + 24576);                 // NE uint2
    int*    off    = (int*)(sorted + NE);                  // NN+1
    int*    bcount = off + NN + 1;                         // NBUK
    int*    bbase  = bcount + NBUK;                        // NBUK+1
    uintptr_t xp = ((uintptr_t)(bbase + NBUK + 1) + 15) & ~(uintptr_t)15;
    _Float16* xh = (_Float16*)xp;                          // NN*64 fp16
    uint2*  tmp    = (uint2*)uv;                           // padded NBUK*BSTRIDE uint2 (19.2MB < 51.2MB)

    hipMemsetAsync(bcount, 0, NBUK * sizeof(int), stream);

    kfront    <<<NTB + NWB + NPB, 256, 0, stream>>>(ei, rf, bcount, tmp,
                 Wp, Wn, w1, w2, cf, wh, wl, x, attw, es1, xh);
    ks_bscan  <<<1, 1024, 0, stream>>>(bcount, bbase);
    kscat2    <<<NBUK, 256, 0, stream>>>(tmp, bcount, bbase, es1, off, sorted);
    k4a_agg   <<<NN/4, 256, 0, stream>>>(sorted, off, xh, uv);
    k4b5      <<<(NN+127)/128, 512, 0, stream>>>(uv, wh, wl, x, g1, be1, b1, b2, g2, be2, out);
}